// Round 2
// baseline (660.412 us; speedup 1.0000x reference)
//
#include <hip/hip_runtime.h>
#include <math.h>

#define N_NODES_C  500000
#define N_EDGES_C  8000000
#define N_GRAPHS_C 1000

// workspace layout (float offsets)
#define GRAPH_ACC_OFF 0          // 11000 floats (1000 graphs x 11 feats)
#define FW_OFF        11008      // 207 floats of fused weights
#define NODE_ACC_OFF  11264      // K * 500000 floats (replicated accumulators)

// fused-weight layout inside fw[]
// 0   : w_pn1[20]   (2x10 row-major)
// 20  : b_pn1[10]
// 30  : W_eb[50]    (10x5) = pn_w2 @ ue_w1[1:,:]
// 80  : b_eb[5]     = pn_b2 @ ue_w1[1:,:] + ue_b1
// 85  : w1r0_e[5]   = ue_w1[0,:]
// 90  : w2_e[5]     = ue_w2
// 95  : b2_e[1]     = ue_b2
// 96  : w_pe1[5]
// 101 : b_pe1[5]
// 106 : pe_w2[50]   (5x10)
// 156 : pe_b2[10]
// 166 : W_nb[25]    (5x5)  = pe_w2 @ un_w1[1:,:]
// 191 : b_nb[5]     = pe_b2 @ un_w1[1:,:] + un_b1
// 196 : w1r0_n[5]   = un_w1[0,:]
// 201 : w2_n[5]     = un_w2
// 206 : b2_n[1]     = un_b2

__device__ __forceinline__ float selu_f(float x) {
    const float scale = 1.0507009873554805f;
    const float sa    = 1.0507009873554805f * 1.6732632423543772f;
    float neg = sa * (__expf(x) - 1.0f);
    return x > 0.0f ? scale * x : neg;
}

__device__ __forceinline__ void atomAddF(float* p, float v) {
    __hip_atomic_fetch_add(p, v, __ATOMIC_RELAXED, __HIP_MEMORY_SCOPE_AGENT);
}

__global__ __launch_bounds__(256) void k_zero(float* __restrict__ ws, int len4) {
    int i = blockIdx.x * 256 + threadIdx.x;
    if (i < len4) ((float4*)ws)[i] = make_float4(0.f, 0.f, 0.f, 0.f);
}

__global__ void k_fuse(const float* __restrict__ pn_w1, const float* __restrict__ pn_b1,
                       const float* __restrict__ pn_w2, const float* __restrict__ pn_b2,
                       const float* __restrict__ ue_w1, const float* __restrict__ ue_b1,
                       const float* __restrict__ ue_w2, const float* __restrict__ ue_b2,
                       const float* __restrict__ pe_w1, const float* __restrict__ pe_b1,
                       const float* __restrict__ pe_w2, const float* __restrict__ pe_b2,
                       const float* __restrict__ un_w1, const float* __restrict__ un_b1,
                       const float* __restrict__ un_w2, const float* __restrict__ un_b2,
                       float* __restrict__ fw) {
    int t = threadIdx.x;
    if (t < 20) fw[0 + t] = pn_w1[t];
    if (t < 10) fw[20 + t] = pn_b1[t];
    if (t < 50) {                       // W_eb (10x5)
        int j = t / 5, k = t % 5;
        float s = 0.0f;
        for (int m = 0; m < 10; ++m) s += pn_w2[j * 10 + m] * ue_w1[(1 + m) * 5 + k];
        fw[30 + t] = s;
    }
    if (t < 5) {                        // b_eb
        float s = ue_b1[t];
        for (int m = 0; m < 10; ++m) s += pn_b2[m] * ue_w1[(1 + m) * 5 + t];
        fw[80 + t] = s;
    }
    if (t < 5)  fw[85 + t]  = ue_w1[t];   // row 0 of ue_w1
    if (t < 5)  fw[90 + t]  = ue_w2[t];
    if (t == 0) fw[95]      = ue_b2[0];
    if (t < 5)  fw[96 + t]  = pe_w1[t];
    if (t < 5)  fw[101 + t] = pe_b1[t];
    if (t < 50) fw[106 + t] = pe_w2[t];
    if (t < 10) fw[156 + t] = pe_b2[t];
    if (t < 25) {                       // W_nb (5x5)
        int j = t / 5, k = t % 5;
        float s = 0.0f;
        for (int m = 0; m < 10; ++m) s += pe_w2[j * 10 + m] * un_w1[(1 + m) * 5 + k];
        fw[166 + t] = s;
    }
    if (t < 5) {                        // b_nb
        float s = un_b1[t];
        for (int m = 0; m < 10; ++m) s += pe_b2[m] * un_w1[(1 + m) * 5 + t];
        fw[191 + t] = s;
    }
    if (t < 5)  fw[196 + t] = un_w1[t];
    if (t < 5)  fw[201 + t] = un_w2[t];
    if (t == 0) fw[206]     = un_b2[0];
}

__global__ __launch_bounds__(256) void k_edges(
        const float* __restrict__ nodes, const float* __restrict__ edges,
        const int* __restrict__ senders, const int* __restrict__ receivers,
        const float* __restrict__ fw, float* __restrict__ node_acc, int kmask) {
    // load fused weights (uniform addresses -> s_loads)
    float w_pn1[20], b_pn1[10], W_eb[50], b_eb[5], w1r0[5], w2e[5];
#pragma unroll
    for (int j = 0; j < 20; ++j) w_pn1[j] = fw[j];
#pragma unroll
    for (int j = 0; j < 10; ++j) b_pn1[j] = fw[20 + j];
#pragma unroll
    for (int j = 0; j < 50; ++j) W_eb[j] = fw[30 + j];
#pragma unroll
    for (int j = 0; j < 5; ++j) b_eb[j] = fw[80 + j];
#pragma unroll
    for (int j = 0; j < 5; ++j) w1r0[j] = fw[85 + j];
#pragma unroll
    for (int j = 0; j < 5; ++j) w2e[j] = fw[90 + j];
    float b2e = fw[95];

    int g = blockIdx.x * 256 + threadIdx.x;       // group of 4 edges
    if (g >= N_EDGES_C / 4) return;

    // replica for this block: spread atomic traffic over K copies
    float* acc = node_acc + (size_t)(blockIdx.x & kmask) * N_NODES_C;

    float4 e4 = ((const float4*)edges)[g];
    int4  s4 = ((const int4*)senders)[g];
    int4  r4 = ((const int4*)receivers)[g];
    float ev[4] = {e4.x, e4.y, e4.z, e4.w};
    int   sv[4] = {s4.x, s4.y, s4.z, s4.w};
    int   rv[4] = {r4.x, r4.y, r4.z, r4.w};

    float nsv[4], nrv[4];
#pragma unroll
    for (int u = 0; u < 4; ++u) { nsv[u] = nodes[sv[u]]; nrv[u] = nodes[rv[u]]; }

#pragma unroll
    for (int u = 0; u < 4; ++u) {
        float nr = nrv[u], ns = nsv[u];
        float base[5];
#pragma unroll
        for (int k = 0; k < 5; ++k) base[k] = b_eb[k];
#pragma unroll
        for (int j = 0; j < 10; ++j) {
            float z  = fmaf(nr, w_pn1[j], fmaf(ns, w_pn1[10 + j], b_pn1[j]));
            float sz = selu_f(z);
#pragma unroll
            for (int k = 0; k < 5; ++k) base[k] = fmaf(sz, W_eb[j * 5 + k], base[k]);
        }
        float e = ev[u];
#pragma unroll
        for (int it = 0; it < 3; ++it) {
            float acc2 = b2e;
#pragma unroll
            for (int k = 0; k < 5; ++k) {
                float tt = selu_f(fmaf(e, w1r0[k], base[k]));
                acc2 = fmaf(tt, w2e[k], acc2);
            }
            e = acc2;
        }
        atomAddF(&acc[rv[u]], e);
    }
}

__global__ __launch_bounds__(256) void k_nodes(
        const float* __restrict__ nodes, const int* __restrict__ graph_ids,
        const float* __restrict__ fw, const float* __restrict__ node_acc,
        float* __restrict__ graph_acc, int K) {
    float w_pe1[5], b_pe1[5], pe_w2[50], pe_b2[10], W_nb[25], b_nb[5], w1r0n[5], w2n[5];
#pragma unroll
    for (int j = 0; j < 5; ++j) w_pe1[j] = fw[96 + j];
#pragma unroll
    for (int j = 0; j < 5; ++j) b_pe1[j] = fw[101 + j];
#pragma unroll
    for (int j = 0; j < 50; ++j) pe_w2[j] = fw[106 + j];
#pragma unroll
    for (int j = 0; j < 10; ++j) pe_b2[j] = fw[156 + j];
#pragma unroll
    for (int j = 0; j < 25; ++j) W_nb[j] = fw[166 + j];
#pragma unroll
    for (int j = 0; j < 5; ++j) b_nb[j] = fw[191 + j];
#pragma unroll
    for (int j = 0; j < 5; ++j) w1r0n[j] = fw[196 + j];
#pragma unroll
    for (int j = 0; j < 5; ++j) w2n[j] = fw[201 + j];
    float b2n = fw[206];

    int i = blockIdx.x * 256 + threadIdx.x;
    bool valid = i < N_NODES_C;
    int ii = valid ? i : (N_NODES_C - 1);

    float s = 0.0f;
    for (int r = 0; r < K; ++r) s += node_acc[(size_t)r * N_NODES_C + ii];

    float t5[5];
#pragma unroll
    for (int k = 0; k < 5; ++k) t5[k] = selu_f(fmaf(s, w_pe1[k], b_pe1[k]));
    float he[10];
#pragma unroll
    for (int m = 0; m < 10; ++m) {
        float acc = pe_b2[m];
#pragma unroll
        for (int k = 0; k < 5; ++k) acc = fmaf(t5[k], pe_w2[k * 10 + m], acc);
        he[m] = acc;
    }
    float base[5];
#pragma unroll
    for (int k = 0; k < 5; ++k) {
        float acc = b_nb[k];
#pragma unroll
        for (int t = 0; t < 5; ++t) acc = fmaf(t5[t], W_nb[t * 5 + k], acc);
        base[k] = acc;
    }
    float n = nodes[ii];
#pragma unroll
    for (int it = 0; it < 3; ++it) {
        float acc = b2n;
#pragma unroll
        for (int k = 0; k < 5; ++k) {
            float tt = selu_f(fmaf(n, w1r0n[k], base[k]));
            acc = fmaf(tt, w2n[k], acc);
        }
        n = acc;
    }

    int gid = valid ? graph_ids[ii] : -1;
    if (!valid) {
        n = 0.0f;
#pragma unroll
        for (int m = 0; m < 10; ++m) he[m] = 0.0f;
    }

    int gid0 = __shfl(gid, 0, 64);
    bool allsame = __all(gid == gid0) && (gid0 >= 0);
    if (allsame) {
        // sorted graph_ids -> whole wave same graph: reduce then 11 atomics
        float v = n;
#pragma unroll
        for (int off = 32; off > 0; off >>= 1) v += __shfl_down(v, off, 64);
        float vh[10];
#pragma unroll
        for (int m = 0; m < 10; ++m) {
            float w = he[m];
#pragma unroll
            for (int off = 32; off > 0; off >>= 1) w += __shfl_down(w, off, 64);
            vh[m] = w;
        }
        if ((threadIdx.x & 63) == 0) {
            atomAddF(&graph_acc[gid0 * 11 + 0], v);
#pragma unroll
            for (int m = 0; m < 10; ++m) atomAddF(&graph_acc[gid0 * 11 + 1 + m], vh[m]);
        }
    } else if (valid) {
        atomAddF(&graph_acc[gid * 11 + 0], n);
#pragma unroll
        for (int m = 0; m < 10; ++m) atomAddF(&graph_acc[gid * 11 + 1 + m], he[m]);
    }
}

__global__ void k_final(const float* __restrict__ graph_acc,
                        const float* __restrict__ pr_w1, const float* __restrict__ pr_b1,
                        const float* __restrict__ pr_w2, const float* __restrict__ pr_b2,
                        float* __restrict__ out) {
    int g = blockIdx.x * blockDim.x + threadIdx.x;
    if (g >= N_GRAPHS_C) return;
    float gv[11];
#pragma unroll
    for (int f = 0; f < 11; ++f) gv[f] = graph_acc[g * 11 + f];
    float h[10];
#pragma unroll
    for (int j = 0; j < 10; ++j) {
        float z = pr_b1[j];
#pragma unroll
        for (int f = 0; f < 11; ++f) z = fmaf(gv[f], pr_w1[f * 10 + j], z);
        h[j] = selu_f(z);
    }
    float o[10];
    float mx = -1e30f;
#pragma unroll
    for (int j = 0; j < 10; ++j) {
        float z = pr_b2[j];
#pragma unroll
        for (int m = 0; m < 10; ++m) z = fmaf(h[m], pr_w2[m * 10 + j], z);
        o[j] = z;
        mx = fmaxf(mx, z);
    }
    float sum = 0.0f;
#pragma unroll
    for (int j = 0; j < 10; ++j) { o[j] = __expf(o[j] - mx); sum += o[j]; }
    float inv = 1.0f / sum;
#pragma unroll
    for (int j = 0; j < 10; ++j) out[g * 10 + j] = o[j] * inv;
}

extern "C" void kernel_launch(void* const* d_in, const int* in_sizes, int n_in,
                              void* d_out, int out_size, void* d_ws, size_t ws_size,
                              hipStream_t stream) {
    const float* nodes     = (const float*)d_in[0];
    const float* edges     = (const float*)d_in[1];
    const int*   senders   = (const int*)d_in[2];
    const int*   receivers = (const int*)d_in[3];
    const int*   graph_ids = (const int*)d_in[4];
    const float* pn_w1 = (const float*)d_in[6];
    const float* pn_b1 = (const float*)d_in[7];
    const float* pn_w2 = (const float*)d_in[8];
    const float* pn_b2 = (const float*)d_in[9];
    const float* ue_w1 = (const float*)d_in[10];
    const float* ue_b1 = (const float*)d_in[11];
    const float* ue_w2 = (const float*)d_in[12];
    const float* ue_b2 = (const float*)d_in[13];
    const float* pe_w1 = (const float*)d_in[14];
    const float* pe_b1 = (const float*)d_in[15];
    const float* pe_w2 = (const float*)d_in[16];
    const float* pe_b2 = (const float*)d_in[17];
    const float* un_w1 = (const float*)d_in[18];
    const float* un_b1 = (const float*)d_in[19];
    const float* un_w2 = (const float*)d_in[20];
    const float* un_b2 = (const float*)d_in[21];
    const float* pr_w1 = (const float*)d_in[22];
    const float* pr_b1 = (const float*)d_in[23];
    const float* pr_w2 = (const float*)d_in[24];
    const float* pr_b2 = (const float*)d_in[25];

    float* ws = (float*)d_ws;
    float* graph_acc = ws + GRAPH_ACC_OFF;
    float* fw        = ws + FW_OFF;
    float* node_acc  = ws + NODE_ACC_OFF;
    float* outp      = (float*)d_out;

    // pick replica count K (power of 2, up to 8) based on workspace size
    long avail = (long)(ws_size / 4) - NODE_ACC_OFF;
    int K = 1;
    while (K < 8 && (long)(K * 2) * N_NODES_C <= avail) K <<= 1;

    int zero_floats = NODE_ACC_OFF + K * N_NODES_C;   // graph_acc+fw+replicas
    int len4 = zero_floats / 4;
    hipLaunchKernelGGL(k_zero, dim3((len4 + 255) / 256), dim3(256), 0, stream, ws, len4);
    hipLaunchKernelGGL(k_fuse, dim3(1), dim3(64), 0, stream,
                       pn_w1, pn_b1, pn_w2, pn_b2, ue_w1, ue_b1, ue_w2, ue_b2,
                       pe_w1, pe_b1, pe_w2, pe_b2, un_w1, un_b1, un_w2, un_b2, fw);
    hipLaunchKernelGGL(k_edges, dim3((N_EDGES_C / 4 + 255) / 256), dim3(256), 0, stream,
                       nodes, edges, senders, receivers, fw, node_acc, K - 1);
    hipLaunchKernelGGL(k_nodes, dim3((N_NODES_C + 255) / 256), dim3(256), 0, stream,
                       nodes, graph_ids, fw, node_acc, graph_acc, K);
    hipLaunchKernelGGL(k_final, dim3((N_GRAPHS_C + 255) / 256), dim3(256), 0, stream,
                       graph_acc, pr_w1, pr_b1, pr_w2, pr_b2, outp);
}

// Round 3
// 437.638 us; speedup vs baseline: 1.5090x; 1.5090x over previous
//
#include <hip/hip_runtime.h>
#include <hip/hip_fp16.h>
#include <math.h>

#define N_NODES_C  500000
#define N_EDGES_C  8000000
#define N_GRAPHS_C 1000

#define NB      256          // bucket slots allocated (245 used)
#define BSHIFT  11           // bucket = recv >> 11  (2048 nodes/bucket)
#define BWIDTH  2048
#define BCAP    34048        // slots/bucket: mean 32768 + ~7 sigma(181); /4 ok

// ---- new-path workspace layout (32-bit word offsets) ----
#define GRAPH_ACC_OFF 0          // 11000 floats
#define FW_OFF        11008      // 207 floats fused weights
#define CURSOR_OFF    11264      // 256 ints
#define PAIRS_OFF     11520      // NB*BCAP uint32
#define WS_WORDS_NEEDED (PAIRS_OFF + NB * BCAP)
// ---- old-path (fallback) layout ----
#define OLD_NODE_ACC_OFF 11264   // 500000 floats
#define OLD_ZERO_WORDS   (OLD_NODE_ACC_OFF + N_NODES_C)

// fused-weight layout inside fw[] (same as rounds 1-2)
// 0:w_pn1[20] 20:b_pn1[10] 30:W_eb[50] 80:b_eb[5] 85:w1r0_e[5] 90:w2_e[5] 95:b2_e
// 96:w_pe1[5] 101:b_pe1[5] 106:pe_w2[50] 156:pe_b2[10] 166:W_nb[25] 191:b_nb[5]
// 196:w1r0_n[5] 201:w2_n[5] 206:b2_n

__device__ __forceinline__ float selu_f(float x) {
    const float scale = 1.0507009873554805f;
    const float sa    = 1.0507009873554805f * 1.6732632423543772f;
    float neg = sa * (__expf(x) - 1.0f);
    return x > 0.0f ? scale * x : neg;
}

__device__ __forceinline__ void atomAddF(float* p, float v) {
    __hip_atomic_fetch_add(p, v, __ATOMIC_RELAXED, __HIP_MEMORY_SCOPE_AGENT);
}

// ---------------- shared tiny kernels ----------------

__global__ void k_fuse(const float* __restrict__ pn_w1, const float* __restrict__ pn_b1,
                       const float* __restrict__ pn_w2, const float* __restrict__ pn_b2,
                       const float* __restrict__ ue_w1, const float* __restrict__ ue_b1,
                       const float* __restrict__ ue_w2, const float* __restrict__ ue_b2,
                       const float* __restrict__ pe_w1, const float* __restrict__ pe_b1,
                       const float* __restrict__ pe_w2, const float* __restrict__ pe_b2,
                       const float* __restrict__ un_w1, const float* __restrict__ un_b1,
                       const float* __restrict__ un_w2, const float* __restrict__ un_b2,
                       float* __restrict__ fw) {
    int t = threadIdx.x;
    if (t < 20) fw[0 + t] = pn_w1[t];
    if (t < 10) fw[20 + t] = pn_b1[t];
    if (t < 50) {                       // W_eb (10x5)
        int j = t / 5, k = t % 5;
        float s = 0.0f;
        for (int m = 0; m < 10; ++m) s += pn_w2[j * 10 + m] * ue_w1[(1 + m) * 5 + k];
        fw[30 + t] = s;
    }
    if (t < 5) {                        // b_eb
        float s = ue_b1[t];
        for (int m = 0; m < 10; ++m) s += pn_b2[m] * ue_w1[(1 + m) * 5 + t];
        fw[80 + t] = s;
    }
    if (t < 5)  fw[85 + t]  = ue_w1[t];
    if (t < 5)  fw[90 + t]  = ue_w2[t];
    if (t == 0) fw[95]      = ue_b2[0];
    if (t < 5)  fw[96 + t]  = pe_w1[t];
    if (t < 5)  fw[101 + t] = pe_b1[t];
    if (t < 50) fw[106 + t] = pe_w2[t];
    if (t < 10) fw[156 + t] = pe_b2[t];
    if (t < 25) {                       // W_nb (5x5)
        int j = t / 5, k = t % 5;
        float s = 0.0f;
        for (int m = 0; m < 10; ++m) s += pe_w2[j * 10 + m] * un_w1[(1 + m) * 5 + k];
        fw[166 + t] = s;
    }
    if (t < 5) {                        // b_nb
        float s = un_b1[t];
        for (int m = 0; m < 10; ++m) s += pe_b2[m] * un_w1[(1 + m) * 5 + t];
        fw[191 + t] = s;
    }
    if (t < 5)  fw[196 + t] = un_w1[t];
    if (t < 5)  fw[201 + t] = un_w2[t];
    if (t == 0) fw[206]     = un_b2[0];
}

__global__ void k_final(const float* __restrict__ graph_acc,
                        const float* __restrict__ pr_w1, const float* __restrict__ pr_b1,
                        const float* __restrict__ pr_w2, const float* __restrict__ pr_b2,
                        float* __restrict__ out) {
    int g = blockIdx.x * blockDim.x + threadIdx.x;
    if (g >= N_GRAPHS_C) return;
    float gv[11];
#pragma unroll
    for (int f = 0; f < 11; ++f) gv[f] = graph_acc[g * 11 + f];
    float h[10];
#pragma unroll
    for (int j = 0; j < 10; ++j) {
        float z = pr_b1[j];
#pragma unroll
        for (int f = 0; f < 11; ++f) z = fmaf(gv[f], pr_w1[f * 10 + j], z);
        h[j] = selu_f(z);
    }
    float o[10];
    float mx = -1e30f;
#pragma unroll
    for (int j = 0; j < 10; ++j) {
        float z = pr_b2[j];
#pragma unroll
        for (int m = 0; m < 10; ++m) z = fmaf(h[m], pr_w2[m * 10 + j], z);
        o[j] = z;
        mx = fmaxf(mx, z);
    }
    float sum = 0.0f;
#pragma unroll
    for (int j = 0; j < 10; ++j) { o[j] = __expf(o[j] - mx); sum += o[j]; }
    float inv = 1.0f / sum;
#pragma unroll
    for (int j = 0; j < 10; ++j) out[g * 10 + j] = o[j] * inv;
}

// ---------------- NEW path ----------------

// init: zero graph_acc, set bucket cursors to region bases
__global__ __launch_bounds__(256) void k_init(float* __restrict__ ws) {
    int i = blockIdx.x * 256 + threadIdx.x;
    if (i < 11000) ws[GRAPH_ACC_OFF + i] = 0.0f;
    if (i < NB) ((int*)ws)[CURSOR_OFF + i] = i * BCAP;
}

// partition: edge MLP + bucketed scatter of packed (idx|fp16 val) pairs.
// block = 256 threads x 64 edges = 16384 edges (4096 float4-groups of 4)
__global__ __launch_bounds__(256) void k_part(
        const float* __restrict__ nodes, const float* __restrict__ edges,
        const int* __restrict__ senders, const int* __restrict__ receivers,
        const float* __restrict__ fw, int* __restrict__ cursor,
        unsigned int* __restrict__ pairs) {
    __shared__ int shb[NB];
    int tid = threadIdx.x;
    shb[tid] = 0;
    __syncthreads();

    const int NGROUPS = N_EDGES_C / 4;            // 2,000,000
    int g0 = blockIdx.x * 4096;

    // ---- phase A: histogram of receiver buckets ----
    for (int r = 0; r < 16; ++r) {
        int g = g0 + r * 256 + tid;
        if (g < NGROUPS) {
            int4 r4 = ((const int4*)receivers)[g];
            atomicAdd(&shb[r4.x >> BSHIFT], 1);
            atomicAdd(&shb[r4.y >> BSHIFT], 1);
            atomicAdd(&shb[r4.z >> BSHIFT], 1);
            atomicAdd(&shb[r4.w >> BSHIFT], 1);
        }
    }
    __syncthreads();

    // ---- phase B: one global cursor atomic per (block,bucket) ----
    int c = shb[tid];
    int base = 0;
    if (c > 0) base = atomicAdd(&cursor[tid], c);
    __syncthreads();
    shb[tid] = base;            // shb now holds absolute write cursor per bucket
    __syncthreads();

    // weights (wave-uniform -> scalar loads)
    float w_pn1[20], b_pn1[10], W_eb[50], b_eb[5], w1r0[5], w2e[5];
#pragma unroll
    for (int j = 0; j < 20; ++j) w_pn1[j] = fw[j];
#pragma unroll
    for (int j = 0; j < 10; ++j) b_pn1[j] = fw[20 + j];
#pragma unroll
    for (int j = 0; j < 50; ++j) W_eb[j] = fw[30 + j];
#pragma unroll
    for (int j = 0; j < 5; ++j) b_eb[j] = fw[80 + j];
#pragma unroll
    for (int j = 0; j < 5; ++j) w1r0[j] = fw[85 + j];
#pragma unroll
    for (int j = 0; j < 5; ++j) w2e[j] = fw[90 + j];
    float b2e = fw[95];

    // ---- phase C: compute edge values, write packed pairs ----
    for (int r = 0; r < 16; ++r) {
        int g = g0 + r * 256 + tid;
        if (g >= NGROUPS) continue;
        float4 e4 = ((const float4*)edges)[g];
        int4  s4 = ((const int4*)senders)[g];
        int4  r4 = ((const int4*)receivers)[g];
        float ev[4] = {e4.x, e4.y, e4.z, e4.w};
        int   sv[4] = {s4.x, s4.y, s4.z, s4.w};
        int   rv[4] = {r4.x, r4.y, r4.z, r4.w};
        float nsv[4], nrv[4];
#pragma unroll
        for (int u = 0; u < 4; ++u) { nsv[u] = nodes[sv[u]]; nrv[u] = nodes[rv[u]]; }
#pragma unroll
        for (int u = 0; u < 4; ++u) {
            float nr = nrv[u], ns = nsv[u];
            float bs[5];
#pragma unroll
            for (int k = 0; k < 5; ++k) bs[k] = b_eb[k];
#pragma unroll
            for (int j = 0; j < 10; ++j) {
                float z  = fmaf(nr, w_pn1[j], fmaf(ns, w_pn1[10 + j], b_pn1[j]));
                float sz = selu_f(z);
#pragma unroll
                for (int k = 0; k < 5; ++k) bs[k] = fmaf(sz, W_eb[j * 5 + k], bs[k]);
            }
            float e = ev[u];
#pragma unroll
            for (int it = 0; it < 3; ++it) {
                float acc2 = b2e;
#pragma unroll
                for (int k = 0; k < 5; ++k) {
                    float tt = selu_f(fmaf(e, w1r0[k], bs[k]));
                    acc2 = fmaf(tt, w2e[k], acc2);
                }
                e = acc2;
            }
            int bkt  = rv[u] >> BSHIFT;
            int slot = atomicAdd(&shb[bkt], 1);
            int lim  = (bkt + 1) * BCAP - 1;
            slot = slot < lim ? slot : lim;       // safety clamp (never expected)
            __half hh = __float2half_rn(e);
            unsigned int pk = ((unsigned int)(rv[u] & (BWIDTH - 1)) << 16)
                            | (unsigned int)__half_as_ushort(hh);
            pairs[slot] = pk;
        }
    }
}

// gather: one block per bucket. LDS-aggregate pairs, node MLP, graph reduce.
__global__ __launch_bounds__(256) void k_gather(
        const float* __restrict__ nodes, const int* __restrict__ graph_ids,
        const float* __restrict__ fw, const int* __restrict__ cursor,
        const unsigned int* __restrict__ pairs, float* __restrict__ graph_acc) {
    __shared__ float acc[BWIDTH];
    __shared__ float garr[16 * 11];
    int tid = threadIdx.x;
    int b   = blockIdx.x;

#pragma unroll
    for (int q = 0; q < BWIDTH / 256; ++q) acc[q * 256 + tid] = 0.0f;
    if (tid < 176) garr[tid] = 0.0f;
    __syncthreads();

    int cnt = cursor[b] - b * BCAP;
    cnt = cnt < 0 ? 0 : (cnt > BCAP ? BCAP : cnt);

    // ---- aggregate pairs into LDS ----
    const uint4* p4 = (const uint4*)(pairs + (size_t)b * BCAP);
    int n4 = cnt >> 2;
    for (int i = tid; i < n4; i += 256) {
        uint4 q = p4[i];
        atomicAdd(&acc[q.x >> 16], __half2float(__ushort_as_half((unsigned short)(q.x & 0xffff))));
        atomicAdd(&acc[q.y >> 16], __half2float(__ushort_as_half((unsigned short)(q.y & 0xffff))));
        atomicAdd(&acc[q.z >> 16], __half2float(__ushort_as_half((unsigned short)(q.z & 0xffff))));
        atomicAdd(&acc[q.w >> 16], __half2float(__ushort_as_half((unsigned short)(q.w & 0xffff))));
    }
    int rem = cnt & 3;
    if (tid < rem) {
        unsigned int q = pairs[(size_t)b * BCAP + (n4 << 2) + tid];
        atomicAdd(&acc[q >> 16], __half2float(__ushort_as_half((unsigned short)(q & 0xffff))));
    }
    __syncthreads();

    // ---- node MLP + graph reduction ----
    float w_pe1[5], b_pe1[5], pe_w2[50], pe_b2[10], W_nb[25], b_nb[5], w1r0n[5], w2n[5];
#pragma unroll
    for (int j = 0; j < 5; ++j) w_pe1[j] = fw[96 + j];
#pragma unroll
    for (int j = 0; j < 5; ++j) b_pe1[j] = fw[101 + j];
#pragma unroll
    for (int j = 0; j < 50; ++j) pe_w2[j] = fw[106 + j];
#pragma unroll
    for (int j = 0; j < 10; ++j) pe_b2[j] = fw[156 + j];
#pragma unroll
    for (int j = 0; j < 25; ++j) W_nb[j] = fw[166 + j];
#pragma unroll
    for (int j = 0; j < 5; ++j) b_nb[j] = fw[191 + j];
#pragma unroll
    for (int j = 0; j < 5; ++j) w1r0n[j] = fw[196 + j];
#pragma unroll
    for (int j = 0; j < 5; ++j) w2n[j] = fw[201 + j];
    float b2n = fw[206];

    int gidBase = graph_ids[b << BSHIFT];   // first node of bucket, always valid

#pragma unroll
    for (int q = 0; q < BWIDTH / 256; ++q) {
        int local = q * 256 + tid;
        int i = (b << BSHIFT) + local;
        bool valid = i < N_NODES_C;

        float s = acc[local];
        float t5[5];
#pragma unroll
        for (int k = 0; k < 5; ++k) t5[k] = selu_f(fmaf(s, w_pe1[k], b_pe1[k]));
        float he[10];
#pragma unroll
        for (int m = 0; m < 10; ++m) {
            float a = pe_b2[m];
#pragma unroll
            for (int k = 0; k < 5; ++k) a = fmaf(t5[k], pe_w2[k * 10 + m], a);
            he[m] = a;
        }
        float bs[5];
#pragma unroll
        for (int k = 0; k < 5; ++k) {
            float a = b_nb[k];
#pragma unroll
            for (int t = 0; t < 5; ++t) a = fmaf(t5[t], W_nb[t * 5 + k], a);
            bs[k] = a;
        }
        float n = valid ? nodes[i] : 0.0f;
#pragma unroll
        for (int it = 0; it < 3; ++it) {
            float a = b2n;
#pragma unroll
            for (int k = 0; k < 5; ++k) {
                float tt = selu_f(fmaf(n, w1r0n[k], bs[k]));
                a = fmaf(tt, w2n[k], a);
            }
            n = a;
        }

        int gid = valid ? graph_ids[i] : -1;
        if (!valid) {
            n = 0.0f;
#pragma unroll
            for (int m = 0; m < 10; ++m) he[m] = 0.0f;
        }

        int gid0 = __shfl(gid, 0, 64);
        bool allsame = __all(gid == gid0) && (gid0 >= 0);
        if (allsame) {
            float v = n;
#pragma unroll
            for (int off = 32; off > 0; off >>= 1) v += __shfl_down(v, off, 64);
            float vh[10];
#pragma unroll
            for (int m = 0; m < 10; ++m) {
                float w = he[m];
#pragma unroll
                for (int off = 32; off > 0; off >>= 1) w += __shfl_down(w, off, 64);
                vh[m] = w;
            }
            if ((tid & 63) == 0) {
                int off = gid0 - gidBase;
                if (off >= 0 && off < 16) {
                    atomicAdd(&garr[off * 11 + 0], v);
#pragma unroll
                    for (int m = 0; m < 10; ++m) atomicAdd(&garr[off * 11 + 1 + m], vh[m]);
                } else {
                    atomAddF(&graph_acc[gid0 * 11 + 0], v);
#pragma unroll
                    for (int m = 0; m < 10; ++m) atomAddF(&graph_acc[gid0 * 11 + 1 + m], vh[m]);
                }
            }
        } else if (valid) {
            int off = gid - gidBase;
            if (off >= 0 && off < 16) {
                atomicAdd(&garr[off * 11 + 0], n);
#pragma unroll
                for (int m = 0; m < 10; ++m) atomicAdd(&garr[off * 11 + 1 + m], he[m]);
            } else {
                atomAddF(&graph_acc[gid * 11 + 0], n);
#pragma unroll
                for (int m = 0; m < 10; ++m) atomAddF(&graph_acc[gid * 11 + 1 + m], he[m]);
            }
        }
    }
    __syncthreads();

    if (tid < 176) {
        float v = garr[tid];
        if (v != 0.0f) {
            int off = tid / 11, f = tid - off * 11;
            int gg = gidBase + off;
            if (gg < N_GRAPHS_C) atomAddF(&graph_acc[gg * 11 + f], v);
        }
    }
}

// ---------------- OLD path (fallback if ws too small) ----------------

__global__ __launch_bounds__(256) void k_zero(float* __restrict__ ws, int len4) {
    int i = blockIdx.x * 256 + threadIdx.x;
    if (i < len4) ((float4*)ws)[i] = make_float4(0.f, 0.f, 0.f, 0.f);
}

__global__ __launch_bounds__(256) void k_edges(
        const float* __restrict__ nodes, const float* __restrict__ edges,
        const int* __restrict__ senders, const int* __restrict__ receivers,
        const float* __restrict__ fw, float* __restrict__ node_acc) {
    float w_pn1[20], b_pn1[10], W_eb[50], b_eb[5], w1r0[5], w2e[5];
#pragma unroll
    for (int j = 0; j < 20; ++j) w_pn1[j] = fw[j];
#pragma unroll
    for (int j = 0; j < 10; ++j) b_pn1[j] = fw[20 + j];
#pragma unroll
    for (int j = 0; j < 50; ++j) W_eb[j] = fw[30 + j];
#pragma unroll
    for (int j = 0; j < 5; ++j) b_eb[j] = fw[80 + j];
#pragma unroll
    for (int j = 0; j < 5; ++j) w1r0[j] = fw[85 + j];
#pragma unroll
    for (int j = 0; j < 5; ++j) w2e[j] = fw[90 + j];
    float b2e = fw[95];

    int g = blockIdx.x * 256 + threadIdx.x;
    if (g >= N_EDGES_C / 4) return;

    float4 e4 = ((const float4*)edges)[g];
    int4  s4 = ((const int4*)senders)[g];
    int4  r4 = ((const int4*)receivers)[g];
    float ev[4] = {e4.x, e4.y, e4.z, e4.w};
    int   sv[4] = {s4.x, s4.y, s4.z, s4.w};
    int   rv[4] = {r4.x, r4.y, r4.z, r4.w};
    float nsv[4], nrv[4];
#pragma unroll
    for (int u = 0; u < 4; ++u) { nsv[u] = nodes[sv[u]]; nrv[u] = nodes[rv[u]]; }
#pragma unroll
    for (int u = 0; u < 4; ++u) {
        float nr = nrv[u], ns = nsv[u];
        float bs[5];
#pragma unroll
        for (int k = 0; k < 5; ++k) bs[k] = b_eb[k];
#pragma unroll
        for (int j = 0; j < 10; ++j) {
            float z  = fmaf(nr, w_pn1[j], fmaf(ns, w_pn1[10 + j], b_pn1[j]));
            float sz = selu_f(z);
#pragma unroll
            for (int k = 0; k < 5; ++k) bs[k] = fmaf(sz, W_eb[j * 5 + k], bs[k]);
        }
        float e = ev[u];
#pragma unroll
        for (int it = 0; it < 3; ++it) {
            float acc2 = b2e;
#pragma unroll
            for (int k = 0; k < 5; ++k) {
                float tt = selu_f(fmaf(e, w1r0[k], bs[k]));
                acc2 = fmaf(tt, w2e[k], acc2);
            }
            e = acc2;
        }
        atomAddF(&node_acc[rv[u]], e);
    }
}

__global__ __launch_bounds__(256) void k_nodes(
        const float* __restrict__ nodes, const int* __restrict__ graph_ids,
        const float* __restrict__ fw, const float* __restrict__ node_acc,
        float* __restrict__ graph_acc) {
    float w_pe1[5], b_pe1[5], pe_w2[50], pe_b2[10], W_nb[25], b_nb[5], w1r0n[5], w2n[5];
#pragma unroll
    for (int j = 0; j < 5; ++j) w_pe1[j] = fw[96 + j];
#pragma unroll
    for (int j = 0; j < 5; ++j) b_pe1[j] = fw[101 + j];
#pragma unroll
    for (int j = 0; j < 50; ++j) pe_w2[j] = fw[106 + j];
#pragma unroll
    for (int j = 0; j < 10; ++j) pe_b2[j] = fw[156 + j];
#pragma unroll
    for (int j = 0; j < 25; ++j) W_nb[j] = fw[166 + j];
#pragma unroll
    for (int j = 0; j < 5; ++j) b_nb[j] = fw[191 + j];
#pragma unroll
    for (int j = 0; j < 5; ++j) w1r0n[j] = fw[196 + j];
#pragma unroll
    for (int j = 0; j < 5; ++j) w2n[j] = fw[201 + j];
    float b2n = fw[206];

    int i = blockIdx.x * 256 + threadIdx.x;
    bool valid = i < N_NODES_C;
    int ii = valid ? i : (N_NODES_C - 1);

    float s = node_acc[ii];
    float t5[5];
#pragma unroll
    for (int k = 0; k < 5; ++k) t5[k] = selu_f(fmaf(s, w_pe1[k], b_pe1[k]));
    float he[10];
#pragma unroll
    for (int m = 0; m < 10; ++m) {
        float a = pe_b2[m];
#pragma unroll
        for (int k = 0; k < 5; ++k) a = fmaf(t5[k], pe_w2[k * 10 + m], a);
        he[m] = a;
    }
    float bs[5];
#pragma unroll
    for (int k = 0; k < 5; ++k) {
        float a = b_nb[k];
#pragma unroll
        for (int t = 0; t < 5; ++t) a = fmaf(t5[t], W_nb[t * 5 + k], a);
        bs[k] = a;
    }
    float n = nodes[ii];
#pragma unroll
    for (int it = 0; it < 3; ++it) {
        float a = b2n;
#pragma unroll
        for (int k = 0; k < 5; ++k) {
            float tt = selu_f(fmaf(n, w1r0n[k], bs[k]));
            a = fmaf(tt, w2n[k], a);
        }
        n = a;
    }

    int gid = valid ? graph_ids[ii] : -1;
    if (!valid) {
        n = 0.0f;
#pragma unroll
        for (int m = 0; m < 10; ++m) he[m] = 0.0f;
    }

    int gid0 = __shfl(gid, 0, 64);
    bool allsame = __all(gid == gid0) && (gid0 >= 0);
    if (allsame) {
        float v = n;
#pragma unroll
        for (int off = 32; off > 0; off >>= 1) v += __shfl_down(v, off, 64);
        float vh[10];
#pragma unroll
        for (int m = 0; m < 10; ++m) {
            float w = he[m];
#pragma unroll
            for (int off = 32; off > 0; off >>= 1) w += __shfl_down(w, off, 64);
            vh[m] = w;
        }
        if ((threadIdx.x & 63) == 0) {
            atomAddF(&graph_acc[gid0 * 11 + 0], v);
#pragma unroll
            for (int m = 0; m < 10; ++m) atomAddF(&graph_acc[gid0 * 11 + 1 + m], vh[m]);
        }
    } else if (valid) {
        atomAddF(&graph_acc[gid * 11 + 0], n);
#pragma unroll
        for (int m = 0; m < 10; ++m) atomAddF(&graph_acc[gid * 11 + 1 + m], he[m]);
    }
}

// ---------------- launch ----------------

extern "C" void kernel_launch(void* const* d_in, const int* in_sizes, int n_in,
                              void* d_out, int out_size, void* d_ws, size_t ws_size,
                              hipStream_t stream) {
    const float* nodes     = (const float*)d_in[0];
    const float* edges     = (const float*)d_in[1];
    const int*   senders   = (const int*)d_in[2];
    const int*   receivers = (const int*)d_in[3];
    const int*   graph_ids = (const int*)d_in[4];
    const float* pn_w1 = (const float*)d_in[6];
    const float* pn_b1 = (const float*)d_in[7];
    const float* pn_w2 = (const float*)d_in[8];
    const float* pn_b2 = (const float*)d_in[9];
    const float* ue_w1 = (const float*)d_in[10];
    const float* ue_b1 = (const float*)d_in[11];
    const float* ue_w2 = (const float*)d_in[12];
    const float* ue_b2 = (const float*)d_in[13];
    const float* pe_w1 = (const float*)d_in[14];
    const float* pe_b1 = (const float*)d_in[15];
    const float* pe_w2 = (const float*)d_in[16];
    const float* pe_b2 = (const float*)d_in[17];
    const float* un_w1 = (const float*)d_in[18];
    const float* un_b1 = (const float*)d_in[19];
    const float* un_w2 = (const float*)d_in[20];
    const float* un_b2 = (const float*)d_in[21];
    const float* pr_w1 = (const float*)d_in[22];
    const float* pr_b1 = (const float*)d_in[23];
    const float* pr_w2 = (const float*)d_in[24];
    const float* pr_b2 = (const float*)d_in[25];

    float* ws        = (float*)d_ws;
    float* graph_acc = ws + GRAPH_ACC_OFF;
    float* fw        = ws + FW_OFF;
    float* outp      = (float*)d_out;

    if (ws_size >= (size_t)WS_WORDS_NEEDED * 4) {
        // ---- new two-phase path ----
        int* cursor          = (int*)ws + CURSOR_OFF;
        unsigned int* pairs  = (unsigned int*)ws + PAIRS_OFF;

        hipLaunchKernelGGL(k_init, dim3(44), dim3(256), 0, stream, ws);
        hipLaunchKernelGGL(k_fuse, dim3(1), dim3(64), 0, stream,
                           pn_w1, pn_b1, pn_w2, pn_b2, ue_w1, ue_b1, ue_w2, ue_b2,
                           pe_w1, pe_b1, pe_w2, pe_b2, un_w1, un_b1, un_w2, un_b2, fw);
        int nblk = (N_EDGES_C / 4 + 4095) / 4096;   // 489
        hipLaunchKernelGGL(k_part, dim3(nblk), dim3(256), 0, stream,
                           nodes, edges, senders, receivers, fw, cursor, pairs);
        int gblk = (N_NODES_C + BWIDTH - 1) / BWIDTH;  // 245
        hipLaunchKernelGGL(k_gather, dim3(gblk), dim3(256), 0, stream,
                           nodes, graph_ids, fw, cursor, pairs, graph_acc);
        hipLaunchKernelGGL(k_final, dim3((N_GRAPHS_C + 255) / 256), dim3(256), 0, stream,
                           graph_acc, pr_w1, pr_b1, pr_w2, pr_b2, outp);
    } else {
        // ---- fallback: round-1 atomic path ----
        float* node_acc = ws + OLD_NODE_ACC_OFF;
        int len4 = OLD_ZERO_WORDS / 4;
        hipLaunchKernelGGL(k_zero, dim3((len4 + 255) / 256), dim3(256), 0, stream, ws, len4);
        hipLaunchKernelGGL(k_fuse, dim3(1), dim3(64), 0, stream,
                           pn_w1, pn_b1, pn_w2, pn_b2, ue_w1, ue_b1, ue_w2, ue_b2,
                           pe_w1, pe_b1, pe_w2, pe_b2, un_w1, un_b1, un_w2, un_b2, fw);
        hipLaunchKernelGGL(k_edges, dim3((N_EDGES_C / 4 + 255) / 256), dim3(256), 0, stream,
                           nodes, edges, senders, receivers, fw, node_acc);
        hipLaunchKernelGGL(k_nodes, dim3((N_NODES_C + 255) / 256), dim3(256), 0, stream,
                           nodes, graph_ids, fw, node_acc, graph_acc);
        hipLaunchKernelGGL(k_final, dim3((N_GRAPHS_C + 255) / 256), dim3(256), 0, stream,
                           graph_acc, pr_w1, pr_b1, pr_w2, pr_b2, outp);
    }
}

// Round 4
// 318.106 us; speedup vs baseline: 2.0761x; 1.3758x over previous
//
#include <hip/hip_runtime.h>
#include <hip/hip_fp16.h>
#include <math.h>

#define N_NODES_C  500000
#define N_EDGES_C  8000000
#define N_GRAPHS_C 1000
#define NGROUPS_C  (N_EDGES_C / 4)     // 2,000,000 float4-groups

#define BSHIFT  11                     // bucket = recv >> 11
#define BWIDTH  2048
#define NBKT    245                    // ceil(500000 / 2048)

#define EPB     8192                   // edges per part-block
#define GPB     (EPB / 4)              // 2048 groups per part-block
#define NPB     ((N_EDGES_C + EPB - 1) / EPB)   // 977 part-blocks
#define SROW    1024                   // starts_T row stride (ints)

// ---- new-path workspace layout (32-bit word offsets) ----
#define GRAPH_ACC_OFF 0                          // 11000 floats
#define FW_OFF        11008                      // 207 floats fused weights
#define STARTS_OFF    11264                      // 246 * SROW ints
#define PAIRS_OFF     (STARTS_OFF + 246 * SROW)  // NPB * EPB uint32
#define WS_WORDS_NEEDED (PAIRS_OFF + NPB * EPB)
// ---- old-path (fallback) layout ----
#define OLD_NODE_ACC_OFF 11264
#define OLD_ZERO_WORDS   (OLD_NODE_ACC_OFF + N_NODES_C)

// fused-weight layout inside fw[]
// 0:w_pn1[20] 20:b_pn1[10] 30:W_eb[50] 80:b_eb[5] 85:w1r0_e[5] 90:w2_e[5] 95:b2_e
// 96:w_pe1[5] 101:b_pe1[5] 106:pe_w2[50] 156:pe_b2[10] 166:W_nb[25] 191:b_nb[5]
// 196:w1r0_n[5] 201:w2_n[5] 206:b2_n

__device__ __forceinline__ float selu_f(float x) {
    const float scale = 1.0507009873554805f;
    const float sa    = 1.0507009873554805f * 1.6732632423543772f;
    float neg = sa * (__expf(x) - 1.0f);
    return x > 0.0f ? scale * x : neg;
}

__device__ __forceinline__ void atomAddF(float* p, float v) {
    __hip_atomic_fetch_add(p, v, __ATOMIC_RELAXED, __HIP_MEMORY_SCOPE_AGENT);
}

__device__ __forceinline__ void fuse_weights(
        int t,
        const float* __restrict__ pn_w1, const float* __restrict__ pn_b1,
        const float* __restrict__ pn_w2, const float* __restrict__ pn_b2,
        const float* __restrict__ ue_w1, const float* __restrict__ ue_b1,
        const float* __restrict__ ue_w2, const float* __restrict__ ue_b2,
        const float* __restrict__ pe_w1, const float* __restrict__ pe_b1,
        const float* __restrict__ pe_w2, const float* __restrict__ pe_b2,
        const float* __restrict__ un_w1, const float* __restrict__ un_b1,
        const float* __restrict__ un_w2, const float* __restrict__ un_b2,
        float* __restrict__ fw) {
    if (t < 20) fw[0 + t] = pn_w1[t];
    if (t < 10) fw[20 + t] = pn_b1[t];
    if (t < 50) {                       // W_eb (10x5)
        int j = t / 5, k = t % 5;
        float s = 0.0f;
        for (int m = 0; m < 10; ++m) s += pn_w2[j * 10 + m] * ue_w1[(1 + m) * 5 + k];
        fw[30 + t] = s;
    }
    if (t < 5) {                        // b_eb
        float s = ue_b1[t];
        for (int m = 0; m < 10; ++m) s += pn_b2[m] * ue_w1[(1 + m) * 5 + t];
        fw[80 + t] = s;
    }
    if (t < 5)  fw[85 + t]  = ue_w1[t];
    if (t < 5)  fw[90 + t]  = ue_w2[t];
    if (t == 0) fw[95]      = ue_b2[0];
    if (t < 5)  fw[96 + t]  = pe_w1[t];
    if (t < 5)  fw[101 + t] = pe_b1[t];
    if (t < 50) fw[106 + t] = pe_w2[t];
    if (t < 10) fw[156 + t] = pe_b2[t];
    if (t < 25) {                       // W_nb (5x5)
        int j = t / 5, k = t % 5;
        float s = 0.0f;
        for (int m = 0; m < 10; ++m) s += pe_w2[j * 10 + m] * un_w1[(1 + m) * 5 + k];
        fw[166 + t] = s;
    }
    if (t < 5) {                        // b_nb
        float s = un_b1[t];
        for (int m = 0; m < 10; ++m) s += pe_b2[m] * un_w1[(1 + m) * 5 + t];
        fw[191 + t] = s;
    }
    if (t < 5)  fw[196 + t] = un_w1[t];
    if (t < 5)  fw[201 + t] = un_w2[t];
    if (t == 0) fw[206]     = un_b2[0];
}

// init: zero graph_acc; block 0 also builds fused weights
__global__ __launch_bounds__(256) void k_init(
        float* __restrict__ ws,
        const float* pn_w1, const float* pn_b1, const float* pn_w2, const float* pn_b2,
        const float* ue_w1, const float* ue_b1, const float* ue_w2, const float* ue_b2,
        const float* pe_w1, const float* pe_b1, const float* pe_w2, const float* pe_b2,
        const float* un_w1, const float* un_b1, const float* un_w2, const float* un_b2) {
    int i = blockIdx.x * 256 + threadIdx.x;
    if (i < 11000) ws[GRAPH_ACC_OFF + i] = 0.0f;
    if (blockIdx.x == 0)
        fuse_weights(threadIdx.x, pn_w1, pn_b1, pn_w2, pn_b2, ue_w1, ue_b1, ue_w2, ue_b2,
                     pe_w1, pe_b1, pe_w2, pe_b2, un_w1, un_b1, un_w2, un_b2, ws + FW_OFF);
}

// standalone fuse (fallback path)
__global__ void k_fuse(const float* pn_w1, const float* pn_b1, const float* pn_w2, const float* pn_b2,
                       const float* ue_w1, const float* ue_b1, const float* ue_w2, const float* ue_b2,
                       const float* pe_w1, const float* pe_b1, const float* pe_w2, const float* pe_b2,
                       const float* un_w1, const float* un_b1, const float* un_w2, const float* un_b2,
                       float* fw) {
    fuse_weights(threadIdx.x, pn_w1, pn_b1, pn_w2, pn_b2, ue_w1, ue_b1, ue_w2, ue_b2,
                 pe_w1, pe_b1, pe_w2, pe_b2, un_w1, un_b1, un_w2, un_b2, fw);
}

__global__ void k_final(const float* __restrict__ graph_acc,
                        const float* __restrict__ pr_w1, const float* __restrict__ pr_b1,
                        const float* __restrict__ pr_w2, const float* __restrict__ pr_b2,
                        float* __restrict__ out) {
    int g = blockIdx.x * blockDim.x + threadIdx.x;
    if (g >= N_GRAPHS_C) return;
    float gv[11];
#pragma unroll
    for (int f = 0; f < 11; ++f) gv[f] = graph_acc[g * 11 + f];
    float h[10];
#pragma unroll
    for (int j = 0; j < 10; ++j) {
        float z = pr_b1[j];
#pragma unroll
        for (int f = 0; f < 11; ++f) z = fmaf(gv[f], pr_w1[f * 10 + j], z);
        h[j] = selu_f(z);
    }
    float o[10];
    float mx = -1e30f;
#pragma unroll
    for (int j = 0; j < 10; ++j) {
        float z = pr_b2[j];
#pragma unroll
        for (int m = 0; m < 10; ++m) z = fmaf(h[m], pr_w2[m * 10 + j], z);
        o[j] = z;
        mx = fmaxf(mx, z);
    }
    float sum = 0.0f;
#pragma unroll
    for (int j = 0; j < 10; ++j) { o[j] = __expf(o[j] - mx); sum += o[j]; }
    float inv = 1.0f / sum;
#pragma unroll
    for (int j = 0; j < 10; ++j) out[g * 10 + j] = o[j] * inv;
}

// ---------------- NEW path ----------------

// partition: edge MLP + block-local counting sort, coalesced flush.
// block = 256 threads, 8192 edges (2048 float4-groups, 8 per thread)
__global__ __launch_bounds__(256) void k_part(
        const float* __restrict__ nodes, const float* __restrict__ edges,
        const int* __restrict__ senders, const int* __restrict__ receivers,
        const float* __restrict__ fw, int* __restrict__ starts_T,
        unsigned int* __restrict__ pairs) {
    __shared__ int hist[256];
    __shared__ int cursorS[256];
    __shared__ uint4 staged4[EPB / 4];
    unsigned int* staged = (unsigned int*)staged4;

    int tid = threadIdx.x;
    int p   = blockIdx.x;
    int gstart = p * GPB;
    int gnum   = NGROUPS_C - gstart;
    if (gnum > GPB) gnum = GPB;

    hist[tid] = 0;
    __syncthreads();

    // ---- phase A: load receivers (kept in regs), histogram buckets ----
    int4 rv4[8];
#pragma unroll
    for (int r = 0; r < 8; ++r) {
        int idx = r * 256 + tid;
        if (idx < gnum) {
            rv4[r] = ((const int4*)receivers)[gstart + idx];
            atomicAdd(&hist[rv4[r].x >> BSHIFT], 1);
            atomicAdd(&hist[rv4[r].y >> BSHIFT], 1);
            atomicAdd(&hist[rv4[r].z >> BSHIFT], 1);
            atomicAdd(&hist[rv4[r].w >> BSHIFT], 1);
        }
    }
    __syncthreads();

    // ---- inclusive scan over 256 buckets (Hillis-Steele) ----
    int orig = hist[tid];
    int val  = orig;
    for (int d = 1; d < 256; d <<= 1) {
        int add = (tid >= d) ? hist[tid - d] : 0;
        __syncthreads();
        if (tid >= d) { val += add; hist[tid] = val; }
        __syncthreads();
    }
    int excl = val - orig;
    cursorS[tid] = excl;
    // excl[245] == total edges of block (buckets >=245 empty)
    if (tid < 246) starts_T[tid * SROW + p] = excl;
    __syncthreads();

    // ---- weights (wave-uniform -> scalar regs) ----
    float w_pn1[20], b_pn1[10], W_eb[50], b_eb[5], w1r0[5], w2e[5];
#pragma unroll
    for (int j = 0; j < 20; ++j) w_pn1[j] = fw[j];
#pragma unroll
    for (int j = 0; j < 10; ++j) b_pn1[j] = fw[20 + j];
#pragma unroll
    for (int j = 0; j < 50; ++j) W_eb[j] = fw[30 + j];
#pragma unroll
    for (int j = 0; j < 5; ++j) b_eb[j] = fw[80 + j];
#pragma unroll
    for (int j = 0; j < 5; ++j) w1r0[j] = fw[85 + j];
#pragma unroll
    for (int j = 0; j < 5; ++j) w2e[j] = fw[90 + j];
    float b2e = fw[95];

    // ---- phase C: edge MLP, counting-sort packed pairs into LDS ----
#pragma unroll
    for (int r = 0; r < 8; ++r) {
        int idx = r * 256 + tid;
        if (idx >= gnum) continue;
        int g = gstart + idx;
        float4 e4 = ((const float4*)edges)[g];
        int4  s4 = ((const int4*)senders)[g];
        float ev[4] = {e4.x, e4.y, e4.z, e4.w};
        int   sv[4] = {s4.x, s4.y, s4.z, s4.w};
        int   rv[4] = {rv4[r].x, rv4[r].y, rv4[r].z, rv4[r].w};
        float nsv[4], nrv[4];
#pragma unroll
        for (int u = 0; u < 4; ++u) { nsv[u] = nodes[sv[u]]; nrv[u] = nodes[rv[u]]; }
#pragma unroll
        for (int u = 0; u < 4; ++u) {
            float nr = nrv[u], ns = nsv[u];
            float bs[5];
#pragma unroll
            for (int k = 0; k < 5; ++k) bs[k] = b_eb[k];
#pragma unroll
            for (int j = 0; j < 10; ++j) {
                float z  = fmaf(nr, w_pn1[j], fmaf(ns, w_pn1[10 + j], b_pn1[j]));
                float sz = selu_f(z);
#pragma unroll
                for (int k = 0; k < 5; ++k) bs[k] = fmaf(sz, W_eb[j * 5 + k], bs[k]);
            }
            float e = ev[u];
#pragma unroll
            for (int it = 0; it < 3; ++it) {
                float acc2 = b2e;
#pragma unroll
                for (int k = 0; k < 5; ++k) {
                    float tt = selu_f(fmaf(e, w1r0[k], bs[k]));
                    acc2 = fmaf(tt, w2e[k], acc2);
                }
                e = acc2;
            }
            int bkt  = rv[u] >> BSHIFT;
            int slot = atomicAdd(&cursorS[bkt], 1);
            unsigned int pk = ((unsigned int)(rv[u] & (BWIDTH - 1)) << 16)
                            | (unsigned int)__half_as_ushort(__float2half_rn(e));
            staged[slot] = pk;
        }
    }
    __syncthreads();

    // ---- flush: contiguous, coalesced uint4 stores ----
    uint4* dst = (uint4*)(pairs + (size_t)p * EPB);
    for (int i = tid; i < gnum; i += 256) dst[i] = staged4[i];
}

// gather: one 1024-thread block per bucket.
__global__ __launch_bounds__(1024) void k_gather(
        const float* __restrict__ nodes, const int* __restrict__ graph_ids,
        const float* __restrict__ fw, const int* __restrict__ starts_T,
        const unsigned int* __restrict__ pairs, float* __restrict__ graph_acc) {
    __shared__ float accf[BWIDTH];
    __shared__ int s0[SROW], s1[SROW];
    __shared__ float garr[16 * 11];
    int tid = threadIdx.x;
    int b   = blockIdx.x;

#pragma unroll
    for (int q = 0; q < BWIDTH / 1024; ++q) accf[q * 1024 + tid] = 0.0f;
    if (tid < 176) garr[tid] = 0.0f;
    for (int i = tid; i < NPB; i += 1024) {
        s0[i] = starts_T[b * SROW + i];
        s1[i] = starts_T[(b + 1) * SROW + i];
    }
    __syncthreads();

    // ---- stream segments, accumulate into LDS ----
    int w = tid >> 6, lane = tid & 63;
    for (int p = w; p < NPB; p += 16) {
        int st = s0[p], en = s1[p];
        const unsigned int* seg = pairs + (size_t)p * EPB + st;
        int cnt = en - st;
        for (int i = lane; i < cnt; i += 64) {
            unsigned int pk = seg[i];
            atomicAdd(&accf[pk >> 16],
                      __half2float(__ushort_as_half((unsigned short)(pk & 0xffff))));
        }
    }
    __syncthreads();

    // ---- node MLP + graph reduction ----
    float w_pe1[5], b_pe1[5], pe_w2[50], pe_b2[10], W_nb[25], b_nb[5], w1r0n[5], w2n[5];
#pragma unroll
    for (int j = 0; j < 5; ++j) w_pe1[j] = fw[96 + j];
#pragma unroll
    for (int j = 0; j < 5; ++j) b_pe1[j] = fw[101 + j];
#pragma unroll
    for (int j = 0; j < 50; ++j) pe_w2[j] = fw[106 + j];
#pragma unroll
    for (int j = 0; j < 10; ++j) pe_b2[j] = fw[156 + j];
#pragma unroll
    for (int j = 0; j < 25; ++j) W_nb[j] = fw[166 + j];
#pragma unroll
    for (int j = 0; j < 5; ++j) b_nb[j] = fw[191 + j];
#pragma unroll
    for (int j = 0; j < 5; ++j) w1r0n[j] = fw[196 + j];
#pragma unroll
    for (int j = 0; j < 5; ++j) w2n[j] = fw[201 + j];
    float b2n = fw[206];

    int gidBase = graph_ids[b << BSHIFT];

#pragma unroll
    for (int q = 0; q < BWIDTH / 1024; ++q) {
        int local = q * 1024 + tid;
        int i = (b << BSHIFT) + local;
        bool valid = i < N_NODES_C;

        float s = accf[local];
        float t5[5];
#pragma unroll
        for (int k = 0; k < 5; ++k) t5[k] = selu_f(fmaf(s, w_pe1[k], b_pe1[k]));
        float he[10];
#pragma unroll
        for (int m = 0; m < 10; ++m) {
            float a = pe_b2[m];
#pragma unroll
            for (int k = 0; k < 5; ++k) a = fmaf(t5[k], pe_w2[k * 10 + m], a);
            he[m] = a;
        }
        float bs[5];
#pragma unroll
        for (int k = 0; k < 5; ++k) {
            float a = b_nb[k];
#pragma unroll
            for (int t = 0; t < 5; ++t) a = fmaf(t5[t], W_nb[t * 5 + k], a);
            bs[k] = a;
        }
        float n = valid ? nodes[i] : 0.0f;
#pragma unroll
        for (int it = 0; it < 3; ++it) {
            float a = b2n;
#pragma unroll
            for (int k = 0; k < 5; ++k) {
                float tt = selu_f(fmaf(n, w1r0n[k], bs[k]));
                a = fmaf(tt, w2n[k], a);
            }
            n = a;
        }

        int gid = valid ? graph_ids[i] : -1;
        if (!valid) {
            n = 0.0f;
#pragma unroll
            for (int m = 0; m < 10; ++m) he[m] = 0.0f;
        }

        int gid0 = __shfl(gid, 0, 64);
        bool allsame = __all(gid == gid0) && (gid0 >= 0);
        if (allsame) {
            float v = n;
#pragma unroll
            for (int off = 32; off > 0; off >>= 1) v += __shfl_down(v, off, 64);
            float vh[10];
#pragma unroll
            for (int m = 0; m < 10; ++m) {
                float ww = he[m];
#pragma unroll
                for (int off = 32; off > 0; off >>= 1) ww += __shfl_down(ww, off, 64);
                vh[m] = ww;
            }
            if ((tid & 63) == 0) {
                int off = gid0 - gidBase;
                if (off >= 0 && off < 16) {
                    atomicAdd(&garr[off * 11 + 0], v);
#pragma unroll
                    for (int m = 0; m < 10; ++m) atomicAdd(&garr[off * 11 + 1 + m], vh[m]);
                } else {
                    atomAddF(&graph_acc[gid0 * 11 + 0], v);
#pragma unroll
                    for (int m = 0; m < 10; ++m) atomAddF(&graph_acc[gid0 * 11 + 1 + m], vh[m]);
                }
            }
        } else if (valid) {
            int off = gid - gidBase;
            if (off >= 0 && off < 16) {
                atomicAdd(&garr[off * 11 + 0], n);
#pragma unroll
                for (int m = 0; m < 10; ++m) atomicAdd(&garr[off * 11 + 1 + m], he[m]);
            } else {
                atomAddF(&graph_acc[gid * 11 + 0], n);
#pragma unroll
                for (int m = 0; m < 10; ++m) atomAddF(&graph_acc[gid * 11 + 1 + m], he[m]);
            }
        }
    }
    __syncthreads();

    if (tid < 176) {
        float v = garr[tid];
        if (v != 0.0f) {
            int off = tid / 11, f = tid - off * 11;
            int gg = gidBase + off;
            if (gg < N_GRAPHS_C) atomAddF(&graph_acc[gg * 11 + f], v);
        }
    }
}

// ---------------- OLD path (fallback if ws too small) ----------------

__global__ __launch_bounds__(256) void k_zero(float* __restrict__ ws, int len4) {
    int i = blockIdx.x * 256 + threadIdx.x;
    if (i < len4) ((float4*)ws)[i] = make_float4(0.f, 0.f, 0.f, 0.f);
}

__global__ __launch_bounds__(256) void k_edges(
        const float* __restrict__ nodes, const float* __restrict__ edges,
        const int* __restrict__ senders, const int* __restrict__ receivers,
        const float* __restrict__ fw, float* __restrict__ node_acc) {
    float w_pn1[20], b_pn1[10], W_eb[50], b_eb[5], w1r0[5], w2e[5];
#pragma unroll
    for (int j = 0; j < 20; ++j) w_pn1[j] = fw[j];
#pragma unroll
    for (int j = 0; j < 10; ++j) b_pn1[j] = fw[20 + j];
#pragma unroll
    for (int j = 0; j < 50; ++j) W_eb[j] = fw[30 + j];
#pragma unroll
    for (int j = 0; j < 5; ++j) b_eb[j] = fw[80 + j];
#pragma unroll
    for (int j = 0; j < 5; ++j) w1r0[j] = fw[85 + j];
#pragma unroll
    for (int j = 0; j < 5; ++j) w2e[j] = fw[90 + j];
    float b2e = fw[95];

    int g = blockIdx.x * 256 + threadIdx.x;
    if (g >= N_EDGES_C / 4) return;

    float4 e4 = ((const float4*)edges)[g];
    int4  s4 = ((const int4*)senders)[g];
    int4  r4 = ((const int4*)receivers)[g];
    float ev[4] = {e4.x, e4.y, e4.z, e4.w};
    int   sv[4] = {s4.x, s4.y, s4.z, s4.w};
    int   rv[4] = {r4.x, r4.y, r4.z, r4.w};
    float nsv[4], nrv[4];
#pragma unroll
    for (int u = 0; u < 4; ++u) { nsv[u] = nodes[sv[u]]; nrv[u] = nodes[rv[u]]; }
#pragma unroll
    for (int u = 0; u < 4; ++u) {
        float nr = nrv[u], ns = nsv[u];
        float bs[5];
#pragma unroll
        for (int k = 0; k < 5; ++k) bs[k] = b_eb[k];
#pragma unroll
        for (int j = 0; j < 10; ++j) {
            float z  = fmaf(nr, w_pn1[j], fmaf(ns, w_pn1[10 + j], b_pn1[j]));
            float sz = selu_f(z);
#pragma unroll
            for (int k = 0; k < 5; ++k) bs[k] = fmaf(sz, W_eb[j * 5 + k], bs[k]);
        }
        float e = ev[u];
#pragma unroll
        for (int it = 0; it < 3; ++it) {
            float acc2 = b2e;
#pragma unroll
            for (int k = 0; k < 5; ++k) {
                float tt = selu_f(fmaf(e, w1r0[k], bs[k]));
                acc2 = fmaf(tt, w2e[k], acc2);
            }
            e = acc2;
        }
        atomAddF(&node_acc[rv[u]], e);
    }
}

__global__ __launch_bounds__(256) void k_nodes(
        const float* __restrict__ nodes, const int* __restrict__ graph_ids,
        const float* __restrict__ fw, const float* __restrict__ node_acc,
        float* __restrict__ graph_acc) {
    float w_pe1[5], b_pe1[5], pe_w2[50], pe_b2[10], W_nb[25], b_nb[5], w1r0n[5], w2n[5];
#pragma unroll
    for (int j = 0; j < 5; ++j) w_pe1[j] = fw[96 + j];
#pragma unroll
    for (int j = 0; j < 5; ++j) b_pe1[j] = fw[101 + j];
#pragma unroll
    for (int j = 0; j < 50; ++j) pe_w2[j] = fw[106 + j];
#pragma unroll
    for (int j = 0; j < 10; ++j) pe_b2[j] = fw[156 + j];
#pragma unroll
    for (int j = 0; j < 25; ++j) W_nb[j] = fw[166 + j];
#pragma unroll
    for (int j = 0; j < 5; ++j) b_nb[j] = fw[191 + j];
#pragma unroll
    for (int j = 0; j < 5; ++j) w1r0n[j] = fw[196 + j];
#pragma unroll
    for (int j = 0; j < 5; ++j) w2n[j] = fw[201 + j];
    float b2n = fw[206];

    int i = blockIdx.x * 256 + threadIdx.x;
    bool valid = i < N_NODES_C;
    int ii = valid ? i : (N_NODES_C - 1);

    float s = node_acc[ii];
    float t5[5];
#pragma unroll
    for (int k = 0; k < 5; ++k) t5[k] = selu_f(fmaf(s, w_pe1[k], b_pe1[k]));
    float he[10];
#pragma unroll
    for (int m = 0; m < 10; ++m) {
        float a = pe_b2[m];
#pragma unroll
        for (int k = 0; k < 5; ++k) a = fmaf(t5[k], pe_w2[k * 10 + m], a);
        he[m] = a;
    }
    float bs[5];
#pragma unroll
    for (int k = 0; k < 5; ++k) {
        float a = b_nb[k];
#pragma unroll
        for (int t = 0; t < 5; ++t) a = fmaf(t5[t], W_nb[t * 5 + k], a);
        bs[k] = a;
    }
    float n = nodes[ii];
#pragma unroll
    for (int it = 0; it < 3; ++it) {
        float a = b2n;
#pragma unroll
        for (int k = 0; k < 5; ++k) {
            float tt = selu_f(fmaf(n, w1r0n[k], bs[k]));
            a = fmaf(tt, w2n[k], a);
        }
        n = a;
    }

    int gid = valid ? graph_ids[ii] : -1;
    if (!valid) {
        n = 0.0f;
#pragma unroll
        for (int m = 0; m < 10; ++m) he[m] = 0.0f;
    }

    int gid0 = __shfl(gid, 0, 64);
    bool allsame = __all(gid == gid0) && (gid0 >= 0);
    if (allsame) {
        float v = n;
#pragma unroll
        for (int off = 32; off > 0; off >>= 1) v += __shfl_down(v, off, 64);
        float vh[10];
#pragma unroll
        for (int m = 0; m < 10; ++m) {
            float ww = he[m];
#pragma unroll
            for (int off = 32; off > 0; off >>= 1) ww += __shfl_down(ww, off, 64);
            vh[m] = ww;
        }
        if ((threadIdx.x & 63) == 0) {
            atomAddF(&graph_acc[gid0 * 11 + 0], v);
#pragma unroll
            for (int m = 0; m < 10; ++m) atomAddF(&graph_acc[gid0 * 11 + 1 + m], vh[m]);
        }
    } else if (valid) {
        atomAddF(&graph_acc[gid * 11 + 0], n);
#pragma unroll
        for (int m = 0; m < 10; ++m) atomAddF(&graph_acc[gid * 11 + 1 + m], he[m]);
    }
}

// ---------------- launch ----------------

extern "C" void kernel_launch(void* const* d_in, const int* in_sizes, int n_in,
                              void* d_out, int out_size, void* d_ws, size_t ws_size,
                              hipStream_t stream) {
    const float* nodes     = (const float*)d_in[0];
    const float* edges     = (const float*)d_in[1];
    const int*   senders   = (const int*)d_in[2];
    const int*   receivers = (const int*)d_in[3];
    const int*   graph_ids = (const int*)d_in[4];
    const float* pn_w1 = (const float*)d_in[6];
    const float* pn_b1 = (const float*)d_in[7];
    const float* pn_w2 = (const float*)d_in[8];
    const float* pn_b2 = (const float*)d_in[9];
    const float* ue_w1 = (const float*)d_in[10];
    const float* ue_b1 = (const float*)d_in[11];
    const float* ue_w2 = (const float*)d_in[12];
    const float* ue_b2 = (const float*)d_in[13];
    const float* pe_w1 = (const float*)d_in[14];
    const float* pe_b1 = (const float*)d_in[15];
    const float* pe_w2 = (const float*)d_in[16];
    const float* pe_b2 = (const float*)d_in[17];
    const float* un_w1 = (const float*)d_in[18];
    const float* un_b1 = (const float*)d_in[19];
    const float* un_w2 = (const float*)d_in[20];
    const float* un_b2 = (const float*)d_in[21];
    const float* pr_w1 = (const float*)d_in[22];
    const float* pr_b1 = (const float*)d_in[23];
    const float* pr_w2 = (const float*)d_in[24];
    const float* pr_b2 = (const float*)d_in[25];

    float* ws        = (float*)d_ws;
    float* graph_acc = ws + GRAPH_ACC_OFF;
    float* fw        = ws + FW_OFF;
    float* outp      = (float*)d_out;

    if (ws_size >= (size_t)WS_WORDS_NEEDED * 4) {
        int* starts_T        = (int*)ws + STARTS_OFF;
        unsigned int* pairs  = (unsigned int*)ws + PAIRS_OFF;

        hipLaunchKernelGGL(k_init, dim3(44), dim3(256), 0, stream, ws,
                           pn_w1, pn_b1, pn_w2, pn_b2, ue_w1, ue_b1, ue_w2, ue_b2,
                           pe_w1, pe_b1, pe_w2, pe_b2, un_w1, un_b1, un_w2, un_b2);
        hipLaunchKernelGGL(k_part, dim3(NPB), dim3(256), 0, stream,
                           nodes, edges, senders, receivers, fw, starts_T, pairs);
        hipLaunchKernelGGL(k_gather, dim3(NBKT), dim3(1024), 0, stream,
                           nodes, graph_ids, fw, starts_T, pairs, graph_acc);
        hipLaunchKernelGGL(k_final, dim3((N_GRAPHS_C + 255) / 256), dim3(256), 0, stream,
                           graph_acc, pr_w1, pr_b1, pr_w2, pr_b2, outp);
    } else {
        float* node_acc = ws + OLD_NODE_ACC_OFF;
        int len4 = OLD_ZERO_WORDS / 4;
        hipLaunchKernelGGL(k_zero, dim3((len4 + 255) / 256), dim3(256), 0, stream, ws, len4);
        hipLaunchKernelGGL(k_fuse, dim3(1), dim3(64), 0, stream,
                           pn_w1, pn_b1, pn_w2, pn_b2, ue_w1, ue_b1, ue_w2, ue_b2,
                           pe_w1, pe_b1, pe_w2, pe_b2, un_w1, un_b1, un_w2, un_b2, fw);
        hipLaunchKernelGGL(k_edges, dim3((N_EDGES_C / 4 + 255) / 256), dim3(256), 0, stream,
                           nodes, edges, senders, receivers, fw, node_acc);
        hipLaunchKernelGGL(k_nodes, dim3((N_NODES_C + 255) / 256), dim3(256), 0, stream,
                           nodes, graph_ids, fw, node_acc, graph_acc);
        hipLaunchKernelGGL(k_final, dim3((N_GRAPHS_C + 255) / 256), dim3(256), 0, stream,
                           graph_acc, pr_w1, pr_b1, pr_w2, pr_b2, outp);
    }
}